// Round 2
// baseline (7565.005 us; speedup 1.0000x reference)
//
#include <hip/hip_runtime.h>
#include <hip/hip_bf16.h>
#include <math.h>

typedef __hip_bfloat16 bf16;

#define BB    32
#define HH    56
#define WWI   56
#define CC    192
#define NHH   6
#define WSS   7
#define NN    49
#define NWIN  64
#define HDD   32
#define LL    (HH*WWI)
#define ROWS  (BB*NWIN*NN)         // 100352
#define TOT   ((size_t)ROWS*CC)    // 19267584
#define SCALEQ 0.17677669529663687f

// canonical bf16 weight buffer element offsets
#define OFF_N1W   0
#define OFF_N1B   384
#define OFF_QKVW  768
#define OFF_QKVB  221952
#define OFF_RPB   223104
#define OFF_PROJW 225132
#define OFF_PROJB 298860
#define OFF_N2W   299244
#define OFF_N2B   299628
#define OFF_F1W   300012
#define OFF_F1B   594924
#define OFF_F2W   596460
#define OFF_F2B   891372
#define WTOT      891756

__device__ __forceinline__ float tof(bf16 v){ return __bfloat162float(v); }
__device__ __forceinline__ bf16  tob(float v){ return __float2bfloat16(v); }
__device__ __forceinline__ float xload(const float* p){ return *p; }
__device__ __forceinline__ float xload(const bf16*  p){ return tof(*p); }
__device__ __forceinline__ void  xstore(float* p, float v){ *p = v; }
__device__ __forceinline__ void  xstore(bf16*  p, float v){ *p = tob(v); }

// ---------- dtype detect: n1w values ~= 1.0 ----------
// bf16 layout: even u16 indices are bf16 elements ~1.0 (0x3F80-ish).
// fp32 layout: even u16 indices are low mantissa halves (uniform random).
__global__ void k_detect(const unsigned short* __restrict__ w, int* __restrict__ flag){
    if (blockIdx.x == 0 && threadIdx.x == 0){
        int cnt = 0;
        for (int k = 0; k < 16; ++k){
            unsigned short u = w[2*k];
            if (u >= 0x3E00 && u <= 0x4100) ++cnt;
        }
        *flag = (cnt >= 8) ? 1 : 0;   // 1 = bf16 inputs, 0 = fp32 inputs
    }
}

// ---------- canonicalize a weight tensor to bf16 ----------
__global__ void k_canon(const void* __restrict__ src, bf16* __restrict__ dst,
                        int n, const int* __restrict__ flag){
    int i = blockIdx.x * blockDim.x + threadIdx.x;
    if (i >= n) return;
    if (*flag) dst[i] = ((const bf16*)src)[i];
    else       dst[i] = tob(((const float*)src)[i]);
}

// ---------- x -> X ----------
template<typename XT>
__global__ void k_convert_in(const void* __restrict__ in, XT* __restrict__ X,
                             const int* __restrict__ flag){
    size_t i = (size_t)blockIdx.x * blockDim.x + threadIdx.x;
    if (i >= TOT) return;
    float v = (*flag) ? tof(((const bf16*)in)[i]) : ((const float*)in)[i];
    xstore(&X[i], v);
}

// ---------- X -> out ----------
template<typename XT>
__global__ void k_out(const XT* __restrict__ X, void* __restrict__ out,
                      const int* __restrict__ flag){
    size_t i = (size_t)blockIdx.x * blockDim.x + threadIdx.x;
    if (i >= TOT) return;
    float v = xload(&X[i]);
    if (*flag) ((bf16*)out)[i] = tob(v);
    else       ((float*)out)[i] = v;
}

// ---------- LN1 + shift + window partition ----------
// grid = ROWS, block = 192 (one row per block, t = channel)
template<typename XT>
__global__ void k_ln_part(const XT* __restrict__ X, const bf16* __restrict__ w,
                          const bf16* __restrict__ bsh, bf16* __restrict__ Hwin,
                          int shift){
    __shared__ float red[CC], red2[CC], stats[2];
    int row = blockIdx.x;
    int t = threadIdx.x;
    int b   = row / (NWIN*NN);
    int win = (row / NN) % NWIN;
    int n   = row % NN;
    int wh = win >> 3, ww = win & 7;
    int iy = n / WSS, ix = n % WSS;
    int sy = (wh*WSS + iy + shift) % HH;
    int sx = (ww*WSS + ix + shift) % WWI;
    const XT* src = X + ((size_t)(b*LL + sy*WWI + sx))*CC;
    float v = xload(&src[t]);
    red[t] = v; red2[t] = v*v;
    __syncthreads();
    for (int off = 96; off >= 3; off >>= 1){
        if (t < off){ red[t] += red[t+off]; red2[t] += red2[t+off]; }
        __syncthreads();
    }
    if (t == 0){
        float su  = red[0] + red[1] + red[2];
        float su2 = red2[0] + red2[1] + red2[2];
        float mu  = su * (1.f/CC);
        float var = su2 * (1.f/CC) - mu*mu;
        stats[0] = mu;
        stats[1] = rsqrtf(var + 1e-5f);
    }
    __syncthreads();
    float o = (v - stats[0]) * stats[1] * tof(w[t]) + tof(bsh[t]);
    Hwin[(size_t)row*CC + t] = tob(o);
}

// ---------- window attention ----------
#define HS_STRIDE 194
#define QK_STRIDE 33
__global__ __launch_bounds__(256) void k_attn(const bf16* __restrict__ Hwin,
        const bf16* __restrict__ qkvw, const bf16* __restrict__ qkvb,
        const bf16* __restrict__ rpb, bf16* __restrict__ AOut, int masked){
    __shared__ bf16  hs[NN*HS_STRIDE];
    __shared__ float qs[NN*QK_STRIDE], ks[NN*QK_STRIDE], vs[NN*QK_STRIDE];
    __shared__ float sc[NN*NN];
    int t = threadIdx.x;
    int win  = blockIdx.x;
    int winl = win % NWIN;
    int wh = winl >> 3, ww = winl & 7;
    const bf16* hg = Hwin + (size_t)win*NN*CC;
    for (int idx = t; idx < NN*CC; idx += 256){
        int i = idx / CC, c = idx % CC;
        hs[i*HS_STRIDE + c] = hg[idx];
    }
    __syncthreads();
    for (int head = 0; head < NHH; ++head){
        for (int task = t; task < 3*NN*HDD; task += 256){
            int m   = task / (NN*HDD);
            int rem = task - m*(NN*HDD);
            int d   = rem / NN;
            int i   = rem % NN;
            int frow = m*CC + head*HDD + d;
            const bf16* wr = qkvw + (size_t)frow*CC;
            const bf16* hr = hs + i*HS_STRIDE;
            float acc = tof(qkvb[frow]);
            for (int c = 0; c < CC; ++c) acc += tof(hr[c]) * tof(wr[c]);
            if (m == 0) acc *= SCALEQ;
            float* dst = (m==0) ? qs : (m==1) ? ks : vs;
            dst[i*QK_STRIDE + d] = acc;
        }
        __syncthreads();
        for (int task = t; task < NN*NN; task += 256){
            int i = task / NN, j = task % NN;
            const float* qi = qs + i*QK_STRIDE;
            const float* kj = ks + j*QK_STRIDE;
            float acc = 0.f;
            #pragma unroll
            for (int d = 0; d < HDD; ++d) acc += qi[d]*kj[d];
            int yi = i/WSS, xi = i%WSS, yj = j/WSS, xj = j%WSS;
            int ridx = (yi - yj + WSS-1)*(2*WSS-1) + (xi - xj + WSS-1);
            acc += tof(rpb[ridx*NHH + head]);
            if (masked){
                int ayi = wh*WSS + yi, axi = ww*WSS + xi;
                int ayj = wh*WSS + yj, axj = ww*WSS + xj;
                int li = ((ayi<49)?0:(ayi<53)?1:2)*3 + ((axi<49)?0:(axi<53)?1:2);
                int lj = ((ayj<49)?0:(ayj<53)?1:2)*3 + ((axj<49)?0:(axj<53)?1:2);
                if (li != lj) acc -= 100.f;
            }
            sc[task] = acc;
        }
        __syncthreads();
        if (t < NN){
            float* r = sc + t*NN;
            float m = -1e30f;
            for (int j = 0; j < NN; ++j) m = fmaxf(m, r[j]);
            float s = 0.f;
            for (int j = 0; j < NN; ++j){ float e = expf(r[j]-m); r[j] = e; s += e; }
            float inv = 1.f/s;
            for (int j = 0; j < NN; ++j) r[j] *= inv;
        }
        __syncthreads();
        for (int task = t; task < NN*HDD; task += 256){
            int i = task / HDD, d = task % HDD;
            const float* pr = sc + i*NN;
            float acc = 0.f;
            for (int j = 0; j < NN; ++j) acc += pr[j]*vs[j*QK_STRIDE + d];
            AOut[(size_t)win*NN*CC + i*CC + head*HDD + d] = tob(acc);
        }
        __syncthreads();
    }
}

// ---------- proj + window reverse + (faithful roll-by-WS bug) + residual ----------
template<typename XT>
__global__ __launch_bounds__(256) void k_proj_res(const bf16* __restrict__ AOut,
        const bf16* __restrict__ pw, const bf16* __restrict__ pb,
        XT* __restrict__ X, int shift){
    __shared__ float as[4*CC];
    int t = threadIdx.x;
    int row0 = blockIdx.x * 4;
    for (int idx = t; idx < 4*CC; idx += 256)
        as[idx] = tof(AOut[(size_t)row0*CC + idx]);
    __syncthreads();
    if (t < CC){
        float a0=0.f, a1=0.f, a2=0.f, a3=0.f;
        const bf16* wr = pw + (size_t)t*CC;
        for (int c = 0; c < CC; ++c){
            float w = tof(wr[c]);
            a0 += as[0*CC+c]*w; a1 += as[1*CC+c]*w;
            a2 += as[2*CC+c]*w; a3 += as[3*CC+c]*w;
        }
        float bias = tof(pb[t]);
        float accs[4] = {a0,a1,a2,a3};
        int roll = (shift > 0) ? WSS : 0;
        for (int r = 0; r < 4; ++r){
            int row = row0 + r;
            int b   = row / (NWIN*NN);
            int win = (row / NN) % NWIN;
            int n   = row % NN;
            int wh = win >> 3, ww = win & 7;
            int iy = n / WSS, ix = n % WSS;
            int y = (wh*WSS + iy + roll) % HH;
            int x = (ww*WSS + ix + roll) % WWI;
            size_t idx = ((size_t)(b*LL + y*WWI + x))*CC + t;
            xstore(&X[idx], xload(&X[idx]) + accs[r] + bias);
        }
    }
}

// ---------- LN2 + FC1 + GELU + FC2 + residual (8 rows/block) ----------
template<typename XT>
__global__ __launch_bounds__(256) void k_mlp(XT* __restrict__ X,
        const bf16* __restrict__ n2w, const bf16* __restrict__ n2b,
        const bf16* __restrict__ w1, const bf16* __restrict__ b1,
        const bf16* __restrict__ w2, const bf16* __restrict__ b2){
    __shared__ float xin[8*CC];
    __shared__ float h1[8*768];
    __shared__ float mus[8], rs[8];
    int t = threadIdx.x;
    size_t row0 = (size_t)blockIdx.x * 8;
    for (int idx = t; idx < 8*CC; idx += 256){
        int r = idx / CC, c = idx % CC;
        xin[idx] = xload(&X[(row0 + r)*CC + c]);
    }
    __syncthreads();
    if (t < 8){
        const float* xr = xin + t*CC;
        float s = 0.f, s2 = 0.f;
        for (int c = 0; c < CC; ++c){ float v = xr[c]; s += v; s2 += v*v; }
        float mu  = s * (1.f/CC);
        float var = s2 * (1.f/CC) - mu*mu;
        mus[t] = mu;
        rs[t]  = rsqrtf(var + 1e-5f);
    }
    __syncthreads();
    for (int idx = t; idx < 8*CC; idx += 256){
        int r = idx / CC, c = idx % CC;
        xin[idx] = (xin[idx] - mus[r]) * rs[r] * tof(n2w[c]) + tof(n2b[c]);
    }
    __syncthreads();
    for (int hd = t; hd < 768; hd += 256){
        const bf16* wr = w1 + (size_t)hd*CC;
        float bb = tof(b1[hd]);
        float acc[8];
        #pragma unroll
        for (int r = 0; r < 8; ++r) acc[r] = bb;
        for (int c = 0; c < CC; ++c){
            float w = tof(wr[c]);
            #pragma unroll
            for (int r = 0; r < 8; ++r) acc[r] += w * xin[r*CC+c];
        }
        #pragma unroll
        for (int r = 0; r < 8; ++r){
            float xv = acc[r];
            h1[r*768+hd] = 0.5f*xv*(1.f + erff(xv*0.70710678118f));
        }
    }
    __syncthreads();
    if (t < CC){
        const bf16* wr = w2 + (size_t)t*768;
        float acc[8] = {0,0,0,0,0,0,0,0};
        for (int h = 0; h < 768; ++h){
            float w = tof(wr[h]);
            #pragma unroll
            for (int r = 0; r < 8; ++r) acc[r] += w * h1[r*768+h];
        }
        float bias = tof(b2[t]);
        #pragma unroll
        for (int r = 0; r < 8; ++r){
            size_t idx = (row0+r)*CC + t;
            xstore(&X[idx], xload(&X[idx]) + acc[r] + bias);
        }
    }
}

// ---------- driver ----------
template<typename XT>
static void run_pipeline(const bf16* wb, const void* xin, int* flag,
                         XT* X, bf16* Hwin, bf16* AOut, void* out,
                         hipStream_t stream){
    k_convert_in<XT><<<(int)(TOT/256), 256, 0, stream>>>(xin, X, flag);
    for (int i = 0; i < 2; ++i){
        int shift = i ? (WSS/2) : 0;
        k_ln_part<XT><<<ROWS, CC, 0, stream>>>(X, wb+OFF_N1W + i*CC,
                wb+OFF_N1B + i*CC, Hwin, shift);
        k_attn<<<BB*NWIN, 256, 0, stream>>>(Hwin,
                wb+OFF_QKVW + (size_t)i*3*CC*CC, wb+OFF_QKVB + (size_t)i*3*CC,
                wb+OFF_RPB + (size_t)i*169*NHH, AOut, i);
        k_proj_res<XT><<<ROWS/4, 256, 0, stream>>>(AOut,
                wb+OFF_PROJW + (size_t)i*CC*CC, wb+OFF_PROJB + i*CC, X, shift);
        k_mlp<XT><<<ROWS/8, 256, 0, stream>>>(X,
                wb+OFF_N2W + i*CC, wb+OFF_N2B + i*CC,
                wb+OFF_F1W + (size_t)i*4*CC*CC, wb+OFF_F1B + (size_t)i*4*CC,
                wb+OFF_F2W + (size_t)i*CC*4*CC, wb+OFF_F2B + i*CC);
    }
    k_out<XT><<<(int)(TOT/256), 256, 0, stream>>>(X, out, flag);
}

extern "C" void kernel_launch(void* const* d_in, const int* in_sizes, int n_in,
                              void* d_out, int out_size, void* d_ws, size_t ws_size,
                              hipStream_t stream){
    char* p = (char*)d_ws;
    int*  flag = (int*)p;                       // 16 B
    bf16* wb   = (bf16*)(p + 16);               // canonical weights, 2 MB region
    char* q    = p + 16 + (2u<<20);

    k_detect<<<1, 64, 0, stream>>>((const unsigned short*)d_in[1], flag);

    static const int widx[13] = {1,2,3,4,5,6,7,8,9,10,11,12,13};
    static const int woff[13] = {OFF_N1W,OFF_N1B,OFF_QKVW,OFF_QKVB,OFF_RPB,
                                 OFF_PROJW,OFF_PROJB,OFF_N2W,OFF_N2B,
                                 OFF_F1W,OFF_F1B,OFF_F2W,OFF_F2B};
    static const int wsz[13]  = {384,384,221184,1152,2028,73728,384,384,384,
                                 294912,1536,294912,384};
    for (int k = 0; k < 13; ++k)
        k_canon<<<(wsz[k]+255)/256, 256, 0, stream>>>(d_in[widx[k]], wb+woff[k],
                                                      wsz[k], flag);

    size_t needF32 = 16 + (2u<<20) + TOT*4 + TOT*2 + TOT*2;
    if (ws_size >= needF32){
        float* X   = (float*)q;       q += TOT*4;
        bf16* Hwin = (bf16*)q;        q += TOT*2;
        bf16* AOut = (bf16*)q;
        run_pipeline<float>(wb, d_in[0], flag, X, Hwin, AOut, d_out, stream);
    } else {
        bf16* X    = (bf16*)q;        q += TOT*2;
        bf16* Hwin = (bf16*)q;        q += TOT*2;
        bf16* AOut = (bf16*)q;
        run_pipeline<bf16>(wb, d_in[0], flag, X, Hwin, AOut, d_out, stream);
    }
}

// Round 3
// 3190.943 us; speedup vs baseline: 2.3708x; 2.3708x over previous
//
#include <hip/hip_runtime.h>
#include <hip/hip_bf16.h>
#include <math.h>

typedef __hip_bfloat16 bf16;

#define BB    32
#define HH    56
#define WWI   56
#define CC    192
#define NHH   6
#define WSS   7
#define NN    49
#define NWIN  64
#define HDD   32
#define LL    (HH*WWI)
#define ROWS  (BB*NWIN*NN)         // 100352
#define TOT   ((size_t)ROWS*CC)    // 19267584
#define SCALEQ 0.17677669529663687f

// canonical bf16 weight buffer element offsets
#define OFF_N1W   0
#define OFF_N1B   384
#define OFF_QKVW  768
#define OFF_QKVB  221952
#define OFF_RPB   223104
#define OFF_PROJW 225132
#define OFF_PROJB 298860
#define OFF_N2W   299244
#define OFF_N2B   299628
#define OFF_F1W   300012
#define OFF_F1B   594924
#define OFF_F2W   596460
#define OFF_F2B   891372

typedef __bf16 bf16x8v __attribute__((ext_vector_type(8)));
typedef float  f32x4   __attribute__((ext_vector_type(4)));

__device__ __forceinline__ float tof(bf16 v){ return __bfloat162float(v); }
__device__ __forceinline__ bf16  tob(float v){ return __float2bfloat16(v); }
__device__ __forceinline__ float xload(const float* p){ return *p; }
__device__ __forceinline__ float xload(const bf16*  p){ return tof(*p); }
__device__ __forceinline__ void  xstore(float* p, float v){ *p = v; }
__device__ __forceinline__ void  xstore(bf16*  p, float v){ *p = tob(v); }

__device__ __forceinline__ bf16x8v ldfrag(const bf16* p){
    return *(const bf16x8v*)p;
}

// ---------- dtype detect ----------
__global__ void k_detect(const unsigned short* __restrict__ w, int* __restrict__ flag){
    if (blockIdx.x == 0 && threadIdx.x == 0){
        int cnt = 0;
        for (int k = 0; k < 16; ++k){
            unsigned short u = w[2*k];
            if (u >= 0x3E00 && u <= 0x4100) ++cnt;
        }
        *flag = (cnt >= 8) ? 1 : 0;
    }
}

__global__ void k_canon(const void* __restrict__ src, bf16* __restrict__ dst,
                        int n, const int* __restrict__ flag){
    int i = blockIdx.x * blockDim.x + threadIdx.x;
    if (i >= n) return;
    if (*flag) dst[i] = ((const bf16*)src)[i];
    else       dst[i] = tob(((const float*)src)[i]);
}

template<typename XT>
__global__ void k_convert_in(const void* __restrict__ in, XT* __restrict__ X,
                             const int* __restrict__ flag){
    size_t i = (size_t)blockIdx.x * blockDim.x + threadIdx.x;
    if (i >= TOT) return;
    float v = (*flag) ? tof(((const bf16*)in)[i]) : ((const float*)in)[i];
    xstore(&X[i], v);
}

template<typename XT>
__global__ void k_out(const XT* __restrict__ X, void* __restrict__ out,
                      const int* __restrict__ flag){
    size_t i = (size_t)blockIdx.x * blockDim.x + threadIdx.x;
    if (i >= TOT) return;
    float v = xload(&X[i]);
    if (*flag) ((bf16*)out)[i] = tob(v);
    else       ((float*)out)[i] = v;
}

// ---------- LN1 + shift + window partition ----------
template<typename XT>
__global__ void k_ln_part(const XT* __restrict__ X, const bf16* __restrict__ w,
                          const bf16* __restrict__ bsh, bf16* __restrict__ Hwin,
                          int shift){
    __shared__ float red[CC], red2[CC], stats[2];
    int row = blockIdx.x;
    int t = threadIdx.x;
    int b   = row / (NWIN*NN);
    int win = (row / NN) % NWIN;
    int n   = row % NN;
    int wh = win >> 3, ww = win & 7;
    int iy = n / WSS, ix = n % WSS;
    int sy = (wh*WSS + iy + shift) % HH;
    int sx = (ww*WSS + ix + shift) % WWI;
    const XT* src = X + ((size_t)(b*LL + sy*WWI + sx))*CC;
    float v = xload(&src[t]);
    red[t] = v; red2[t] = v*v;
    __syncthreads();
    for (int off = 96; off >= 3; off >>= 1){
        if (t < off){ red[t] += red[t+off]; red2[t] += red2[t+off]; }
        __syncthreads();
    }
    if (t == 0){
        float su  = red[0] + red[1] + red[2];
        float su2 = red2[0] + red2[1] + red2[2];
        float mu  = su * (1.f/CC);
        float var = su2 * (1.f/CC) - mu*mu;
        stats[0] = mu;
        stats[1] = rsqrtf(var + 1e-5f);
    }
    __syncthreads();
    float o = (v - stats[0]) * stats[1] * tof(w[t]) + tof(bsh[t]);
    Hwin[(size_t)row*CC + t] = tob(o);
}

// ---------- window attention (VALU, unchanged this round) ----------
#define HS_STRIDE 194
#define QK_STRIDE 33
__global__ __launch_bounds__(256) void k_attn(const bf16* __restrict__ Hwin,
        const bf16* __restrict__ qkvw, const bf16* __restrict__ qkvb,
        const bf16* __restrict__ rpb, bf16* __restrict__ AOut, int masked){
    __shared__ bf16  hs[NN*HS_STRIDE];
    __shared__ float qs[NN*QK_STRIDE], ks[NN*QK_STRIDE], vs[NN*QK_STRIDE];
    __shared__ float sc[NN*NN];
    int t = threadIdx.x;
    int win  = blockIdx.x;
    int winl = win % NWIN;
    int wh = winl >> 3, ww = winl & 7;
    const bf16* hg = Hwin + (size_t)win*NN*CC;
    for (int idx = t; idx < NN*CC; idx += 256){
        int i = idx / CC, c = idx % CC;
        hs[i*HS_STRIDE + c] = hg[idx];
    }
    __syncthreads();
    for (int head = 0; head < NHH; ++head){
        for (int task = t; task < 3*NN*HDD; task += 256){
            int m   = task / (NN*HDD);
            int rem = task - m*(NN*HDD);
            int d   = rem / NN;
            int i   = rem % NN;
            int frow = m*CC + head*HDD + d;
            const bf16* wr = qkvw + (size_t)frow*CC;
            const bf16* hr = hs + i*HS_STRIDE;
            float acc = tof(qkvb[frow]);
            for (int c = 0; c < CC; ++c) acc += tof(hr[c]) * tof(wr[c]);
            if (m == 0) acc *= SCALEQ;
            float* dst = (m==0) ? qs : (m==1) ? ks : vs;
            dst[i*QK_STRIDE + d] = acc;
        }
        __syncthreads();
        for (int task = t; task < NN*NN; task += 256){
            int i = task / NN, j = task % NN;
            const float* qi = qs + i*QK_STRIDE;
            const float* kj = ks + j*QK_STRIDE;
            float acc = 0.f;
            #pragma unroll
            for (int d = 0; d < HDD; ++d) acc += qi[d]*kj[d];
            int yi = i/WSS, xi = i%WSS, yj = j/WSS, xj = j%WSS;
            int ridx = (yi - yj + WSS-1)*(2*WSS-1) + (xi - xj + WSS-1);
            acc += tof(rpb[ridx*NHH + head]);
            if (masked){
                int ayi = wh*WSS + yi, axi = ww*WSS + xi;
                int ayj = wh*WSS + yj, axj = ww*WSS + xj;
                int li = ((ayi<49)?0:(ayi<53)?1:2)*3 + ((axi<49)?0:(axi<53)?1:2);
                int lj = ((ayj<49)?0:(ayj<53)?1:2)*3 + ((axj<49)?0:(axj<53)?1:2);
                if (li != lj) acc -= 100.f;
            }
            sc[task] = acc;
        }
        __syncthreads();
        if (t < NN){
            float* r = sc + t*NN;
            float m = -1e30f;
            for (int j = 0; j < NN; ++j) m = fmaxf(m, r[j]);
            float s = 0.f;
            for (int j = 0; j < NN; ++j){ float e = expf(r[j]-m); r[j] = e; s += e; }
            float inv = 1.f/s;
            for (int j = 0; j < NN; ++j) r[j] *= inv;
        }
        __syncthreads();
        for (int task = t; task < NN*HDD; task += 256){
            int i = task / HDD, d = task % HDD;
            const float* pr = sc + i*NN;
            float acc = 0.f;
            for (int j = 0; j < NN; ++j) acc += pr[j]*vs[j*QK_STRIDE + d];
            AOut[(size_t)win*NN*CC + i*CC + head*HDD + d] = tob(acc);
        }
        __syncthreads();
    }
}

// ---------- proj (MFMA) + window reverse + roll-by-WS bug + residual ----------
// 32 rows/block, 256 threads (4 waves), N=192 K=192
#define AS_STRIDE 200
template<typename XT>
__global__ __launch_bounds__(256) void k_proj_res(const bf16* __restrict__ AOut,
        const bf16* __restrict__ pw, const bf16* __restrict__ pb,
        XT* __restrict__ X, int shift){
    __shared__ bf16 as[32*AS_STRIDE];
    int t = threadIdx.x;
    int row0 = blockIdx.x * 32;
    for (int idx = t; idx < 32*CC; idx += 256){
        int r = idx / CC, c = idx % CC;
        as[r*AS_STRIDE + c] = AOut[(size_t)(row0 + r)*CC + c];
    }
    __syncthreads();
    int wv = t >> 6, lane = t & 63;
    int li16 = lane & 15, quad = lane >> 4;
    int roll = (shift > 0) ? WSS : 0;
    for (int nt = 0; nt < 3; ++nt){
        int n0 = wv*48 + nt*16;
        int col = n0 + li16;
        bf16x8v bfr[6];
        #pragma unroll
        for (int kc = 0; kc < 6; ++kc)
            bfr[kc] = ldfrag(pw + (size_t)col*CC + kc*32 + quad*8);
        float bias = tof(pb[col]);
        for (int mt = 0; mt < 2; ++mt){
            int m0 = mt*16;
            f32x4 acc = {0.f,0.f,0.f,0.f};
            #pragma unroll
            for (int kc = 0; kc < 6; ++kc){
                bf16x8v afr = ldfrag(as + (m0 + li16)*AS_STRIDE + kc*32 + quad*8);
                acc = __builtin_amdgcn_mfma_f32_16x16x32_bf16(afr, bfr[kc], acc, 0, 0, 0);
            }
            #pragma unroll
            for (int r = 0; r < 4; ++r){
                int grow = row0 + m0 + quad*4 + r;
                int b   = grow / (NWIN*NN);
                int rem = grow % (NWIN*NN);
                int win = rem / NN;
                int n   = rem % NN;
                int wh = win >> 3, ww = win & 7;
                int iy = n / WSS, ix = n % WSS;
                int y = (wh*WSS + iy + roll) % HH;
                int x = (ww*WSS + ix + roll) % WWI;
                size_t idx = ((size_t)(b*LL + y*WWI + x))*CC + col;
                xstore(&X[idx], xload(&X[idx]) + acc[r] + bias);
            }
        }
    }
}

// ---------- LN2 + FC1(MFMA) + GELU + FC2(MFMA) + residual ----------
// 32 rows/block, 256 threads (4 waves)
#define H1_STRIDE 776
template<typename XT>
__global__ __launch_bounds__(256) void k_mlp(XT* __restrict__ X,
        const bf16* __restrict__ n2w, const bf16* __restrict__ n2b,
        const bf16* __restrict__ w1, const bf16* __restrict__ b1,
        const bf16* __restrict__ w2, const bf16* __restrict__ b2){
    __shared__ bf16  xin[32*AS_STRIDE];      // 12.8 KB
    __shared__ bf16  h1[32*H1_STRIDE];       // 49.7 KB
    __shared__ float part[256], part2[256];
    __shared__ float stats[64];
    int t = threadIdx.x;
    size_t row0 = (size_t)blockIdx.x * 32;
    // LN2 stats: 8 partials per row
    {
        int r = t >> 3, s = t & 7;
        const XT* xr = X + (row0 + r)*CC + s*24;
        float sm = 0.f, sm2 = 0.f;
        #pragma unroll
        for (int c = 0; c < 24; ++c){ float v = xload(&xr[c]); sm += v; sm2 += v*v; }
        part[t] = sm; part2[t] = sm2;
    }
    __syncthreads();
    if (t < 32){
        float s = 0.f, s2 = 0.f;
        #pragma unroll
        for (int k = 0; k < 8; ++k){ s += part[t*8+k]; s2 += part2[t*8+k]; }
        float mu  = s * (1.f/CC);
        float var = s2 * (1.f/CC) - mu*mu;
        stats[t]      = mu;
        stats[32 + t] = rsqrtf(var + 1e-5f);
    }
    __syncthreads();
    for (int idx = t; idx < 32*CC; idx += 256){
        int r = idx / CC, c = idx % CC;
        float v = xload(&X[(row0 + r)*CC + c]);
        xin[r*AS_STRIDE + c] = tob((v - stats[r]) * stats[32+r] * tof(n2w[c]) + tof(n2b[c]));
    }
    __syncthreads();
    int wv = t >> 6, lane = t & 63;
    int li16 = lane & 15, quad = lane >> 4;
    // FC1: wave wv covers cols [wv*192, wv*192+192)
    for (int nt = 0; nt < 12; ++nt){
        int n0 = wv*192 + nt*16;
        int col = n0 + li16;
        bf16x8v bfr[6];
        #pragma unroll
        for (int kc = 0; kc < 6; ++kc)
            bfr[kc] = ldfrag(w1 + (size_t)col*CC + kc*32 + quad*8);
        float bb = tof(b1[col]);
        for (int mt = 0; mt < 2; ++mt){
            int m0 = mt*16;
            f32x4 acc = {0.f,0.f,0.f,0.f};
            #pragma unroll
            for (int kc = 0; kc < 6; ++kc){
                bf16x8v afr = ldfrag(xin + (m0 + li16)*AS_STRIDE + kc*32 + quad*8);
                acc = __builtin_amdgcn_mfma_f32_16x16x32_bf16(afr, bfr[kc], acc, 0, 0, 0);
            }
            #pragma unroll
            for (int r = 0; r < 4; ++r){
                int mrow = m0 + quad*4 + r;
                float xv = acc[r] + bb;
                float g  = 0.5f*xv*(1.f + erff(xv*0.70710678118f));
                h1[mrow*H1_STRIDE + col] = tob(g);
            }
        }
    }
    __syncthreads();
    // FC2: wave wv covers cols [wv*48, wv*48+48), K=768
    for (int nt = 0; nt < 3; ++nt){
        int n0 = wv*48 + nt*16;
        int col = n0 + li16;
        f32x4 acc0 = {0.f,0.f,0.f,0.f};
        f32x4 acc1 = {0.f,0.f,0.f,0.f};
        for (int kc = 0; kc < 24; ++kc){
            bf16x8v bfr = ldfrag(w2 + (size_t)col*768 + kc*32 + quad*8);
            bf16x8v a0  = ldfrag(h1 + (0  + li16)*H1_STRIDE + kc*32 + quad*8);
            bf16x8v a1  = ldfrag(h1 + (16 + li16)*H1_STRIDE + kc*32 + quad*8);
            acc0 = __builtin_amdgcn_mfma_f32_16x16x32_bf16(a0, bfr, acc0, 0, 0, 0);
            acc1 = __builtin_amdgcn_mfma_f32_16x16x32_bf16(a1, bfr, acc1, 0, 0, 0);
        }
        float bias = tof(b2[col]);
        #pragma unroll
        for (int r = 0; r < 4; ++r){
            size_t i0 = (row0 + 0  + quad*4 + r)*CC + col;
            size_t i1 = (row0 + 16 + quad*4 + r)*CC + col;
            xstore(&X[i0], xload(&X[i0]) + acc0[r] + bias);
            xstore(&X[i1], xload(&X[i1]) + acc1[r] + bias);
        }
    }
}

// ---------- driver ----------
template<typename XT>
static void run_pipeline(const bf16* wb, const void* xin, int* flag,
                         XT* X, bf16* Hwin, bf16* AOut, void* out,
                         hipStream_t stream){
    k_convert_in<XT><<<(int)(TOT/256), 256, 0, stream>>>(xin, X, flag);
    for (int i = 0; i < 2; ++i){
        int shift = i ? (WSS/2) : 0;
        k_ln_part<XT><<<ROWS, CC, 0, stream>>>(X, wb+OFF_N1W + i*CC,
                wb+OFF_N1B + i*CC, Hwin, shift);
        k_attn<<<BB*NWIN, 256, 0, stream>>>(Hwin,
                wb+OFF_QKVW + (size_t)i*3*CC*CC, wb+OFF_QKVB + (size_t)i*3*CC,
                wb+OFF_RPB + (size_t)i*169*NHH, AOut, i);
        k_proj_res<XT><<<ROWS/32, 256, 0, stream>>>(AOut,
                wb+OFF_PROJW + (size_t)i*CC*CC, wb+OFF_PROJB + i*CC, X, shift);
        k_mlp<XT><<<ROWS/32, 256, 0, stream>>>(X,
                wb+OFF_N2W + i*CC, wb+OFF_N2B + i*CC,
                wb+OFF_F1W + (size_t)i*4*CC*CC, wb+OFF_F1B + (size_t)i*4*CC,
                wb+OFF_F2W + (size_t)i*CC*4*CC, wb+OFF_F2B + i*CC);
    }
    k_out<XT><<<(int)(TOT/256), 256, 0, stream>>>(X, out, flag);
}

extern "C" void kernel_launch(void* const* d_in, const int* in_sizes, int n_in,
                              void* d_out, int out_size, void* d_ws, size_t ws_size,
                              hipStream_t stream){
    char* p = (char*)d_ws;
    int*  flag = (int*)p;
    bf16* wb   = (bf16*)(p + 16);
    char* q    = p + 16 + (2u<<20);

    k_detect<<<1, 64, 0, stream>>>((const unsigned short*)d_in[1], flag);

    static const int widx[13] = {1,2,3,4,5,6,7,8,9,10,11,12,13};
    static const int woff[13] = {OFF_N1W,OFF_N1B,OFF_QKVW,OFF_QKVB,OFF_RPB,
                                 OFF_PROJW,OFF_PROJB,OFF_N2W,OFF_N2B,
                                 OFF_F1W,OFF_F1B,OFF_F2W,OFF_F2B};
    static const int wsz[13]  = {384,384,221184,1152,2028,73728,384,384,384,
                                 294912,1536,294912,384};
    for (int k = 0; k < 13; ++k)
        k_canon<<<(wsz[k]+255)/256, 256, 0, stream>>>(d_in[widx[k]], wb+woff[k],
                                                      wsz[k], flag);

    size_t needF32 = 16 + (2u<<20) + TOT*4 + TOT*2 + TOT*2;
    if (ws_size >= needF32){
        float* X   = (float*)q;       q += TOT*4;
        bf16* Hwin = (bf16*)q;        q += TOT*2;
        bf16* AOut = (bf16*)q;
        run_pipeline<float>(wb, d_in[0], flag, X, Hwin, AOut, d_out, stream);
    } else {
        bf16* X    = (bf16*)q;        q += TOT*2;
        bf16* Hwin = (bf16*)q;        q += TOT*2;
        bf16* AOut = (bf16*)q;
        run_pipeline<bf16>(wb, d_in[0], flag, X, Hwin, AOut, d_out, stream);
    }
}

// Round 5
// 1654.316 us; speedup vs baseline: 4.5729x; 1.9289x over previous
//
#include <hip/hip_runtime.h>
#include <hip/hip_bf16.h>
#include <math.h>

typedef __hip_bfloat16 bf16;

#define BB    32
#define HH    56
#define WWI   56
#define CC    192
#define NHH   6
#define WSS   7
#define NN    49
#define NWIN  64
#define HDD   32
#define LL    (HH*WWI)
#define ROWS  (BB*NWIN*NN)         // 100352
#define TOT   ((size_t)ROWS*CC)    // 19267584
#define SCALEQ 0.17677669529663687f

// canonical bf16 weight buffer element offsets
#define OFF_N1W   0
#define OFF_N1B   384
#define OFF_QKVW  768
#define OFF_QKVB  221952
#define OFF_RPB   223104
#define OFF_PROJW 225132
#define OFF_PROJB 298860
#define OFF_N2W   299244
#define OFF_N2B   299628
#define OFF_F1W   300012
#define OFF_F1B   594924
#define OFF_F2W   596460
#define OFF_F2B   891372

typedef __bf16 bf16x8v __attribute__((ext_vector_type(8)));
typedef float  f32x4   __attribute__((ext_vector_type(4)));

__device__ __forceinline__ float tof(bf16 v){ return __bfloat162float(v); }
__device__ __forceinline__ bf16  tob(float v){ return __float2bfloat16(v); }
__device__ __forceinline__ float xload(const float* p){ return *p; }
__device__ __forceinline__ float xload(const bf16*  p){ return tof(*p); }
__device__ __forceinline__ void  xstore(float* p, float v){ *p = v; }
__device__ __forceinline__ void  xstore(bf16*  p, float v){ *p = tob(v); }

__device__ __forceinline__ bf16x8v ldfrag(const bf16* p){
    return *(const bf16x8v*)p;
}

// ---------- dtype detect ----------
__global__ void k_detect(const unsigned short* __restrict__ w, int* __restrict__ flag){
    if (blockIdx.x == 0 && threadIdx.x == 0){
        int cnt = 0;
        for (int k = 0; k < 16; ++k){
            unsigned short u = w[2*k];
            if (u >= 0x3E00 && u <= 0x4100) ++cnt;
        }
        *flag = (cnt >= 8) ? 1 : 0;
    }
}

__global__ void k_canon(const void* __restrict__ src, bf16* __restrict__ dst,
                        int n, const int* __restrict__ flag){
    int i = blockIdx.x * blockDim.x + threadIdx.x;
    if (i >= n) return;
    if (*flag) dst[i] = ((const bf16*)src)[i];
    else       dst[i] = tob(((const float*)src)[i]);
}

template<typename XT>
__global__ void k_convert_in(const void* __restrict__ in, XT* __restrict__ X,
                             const int* __restrict__ flag){
    size_t i = (size_t)blockIdx.x * blockDim.x + threadIdx.x;
    if (i >= TOT) return;
    float v = (*flag) ? tof(((const bf16*)in)[i]) : ((const float*)in)[i];
    xstore(&X[i], v);
}

template<typename XT>
__global__ void k_out(const XT* __restrict__ X, void* __restrict__ out,
                      const int* __restrict__ flag){
    size_t i = (size_t)blockIdx.x * blockDim.x + threadIdx.x;
    if (i >= TOT) return;
    float v = xload(&X[i]);
    if (*flag) ((bf16*)out)[i] = tob(v);
    else       ((float*)out)[i] = v;
}

// ---------- LN1 + shift + window partition ----------
template<typename XT>
__global__ void k_ln_part(const XT* __restrict__ X, const bf16* __restrict__ w,
                          const bf16* __restrict__ bsh, bf16* __restrict__ Hwin,
                          int shift){
    __shared__ float red[CC], red2[CC], stats[2];
    int row = blockIdx.x;
    int t = threadIdx.x;
    int b   = row / (NWIN*NN);
    int win = (row / NN) % NWIN;
    int n   = row % NN;
    int wh = win >> 3, ww = win & 7;
    int iy = n / WSS, ix = n % WSS;
    int sy = (wh*WSS + iy + shift) % HH;
    int sx = (ww*WSS + ix + shift) % WWI;
    const XT* src = X + ((size_t)(b*LL + sy*WWI + sx))*CC;
    float v = xload(&src[t]);
    red[t] = v; red2[t] = v*v;
    __syncthreads();
    for (int off = 96; off >= 3; off >>= 1){
        if (t < off){ red[t] += red[t+off]; red2[t] += red2[t+off]; }
        __syncthreads();
    }
    if (t == 0){
        float su  = red[0] + red[1] + red[2];
        float su2 = red2[0] + red2[1] + red2[2];
        float mu  = su * (1.f/CC);
        float var = su2 * (1.f/CC) - mu*mu;
        stats[0] = mu;
        stats[1] = rsqrtf(var + 1e-5f);
    }
    __syncthreads();
    float o = (v - stats[0]) * stats[1] * tof(w[t]) + tof(bsh[t]);
    Hwin[(size_t)row*CC + t] = tob(o);
}

// ---------- window attention, MFMA ----------
// one block (512 thr, 8 waves) per window. M/N tile starts {0,16,32,33}.
#define HS_ST 200
#define QK_ST 40
#define VT_ST 88
#define SC_ST 53
#define P_ST  72
__device__ __forceinline__ int mt0(int i){ return (i < 3) ? i*16 : 33; }

__global__ __launch_bounds__(512) void k_attn(const bf16* __restrict__ Hwin,
        const bf16* __restrict__ qkvw, const bf16* __restrict__ qkvb,
        const bf16* __restrict__ rpb, bf16* __restrict__ AOut, int masked){
    __shared__ bf16  hs[NN*HS_ST];     // 19.6 KB
    __shared__ bf16  qh[NN*QK_ST];     // 3.9 KB
    __shared__ bf16  kh[NN*QK_ST];     // 3.9 KB
    __shared__ bf16  vT[HDD*VT_ST];    // 5.6 KB
    __shared__ float sc[NN*SC_ST];     // 10.4 KB
    __shared__ bf16  P [NN*P_ST];      // 7.1 KB
    int t = threadIdx.x;
    int win  = blockIdx.x;
    int winl = win & (NWIN-1);
    int wh = winl >> 3, ww = winl & 7;

    // stage h (49x192) into LDS, 16B chunks
    const bf16* hg = Hwin + (size_t)win*NN*CC;
    for (int idx = t; idx < NN*(CC/8); idx += 512){
        int r = idx / (CC/8), c8 = idx % (CC/8);
        *(bf16x8v*)(hs + r*HS_ST + c8*8) = ldfrag(hg + r*CC + c8*8);
    }
    // zero vT (pad cols >=49 must be 0 for PV; cols<49 rewritten per head)
    for (int idx = t; idx < HDD*VT_ST; idx += 512) vT[idx] = tob(0.f);
    __syncthreads();

    int wv = t >> 6, lane = t & 63;
    int li16 = lane & 15, quad = lane >> 4;

    for (int h = 0; h < NHH; ++h){
        // ---- phase 1: q,k,v for head h.  24 tiles = 4 mt x 6 nt ----
        {
            int mt = wv & 3;
            int m0 = mt0(mt);
            bf16x8v afr[6];
            #pragma unroll
            for (int kc = 0; kc < 6; ++kc)
                afr[kc] = ldfrag(hs + (m0 + li16)*HS_ST + kc*32 + quad*8);
            #pragma unroll
            for (int i = 0; i < 3; ++i){
                int tau = wv + 8*i;          // 0..23
                int nt  = tau >> 2;          // 0..5
                int m   = nt >> 1;           // 0=q,1=k,2=v
                int dl  = (nt & 1)*16 + li16;          // 0..31 within head
                int col = m*CC + h*HDD + dl;           // qkv output channel
                float bias = tof(qkvb[col]);
                f32x4 acc = {0.f,0.f,0.f,0.f};
                #pragma unroll
                for (int kc = 0; kc < 6; ++kc){
                    bf16x8v bfr = ldfrag(qkvw + (size_t)col*CC + kc*32 + quad*8);
                    acc = __builtin_amdgcn_mfma_f32_16x16x32_bf16(afr[kc], bfr, acc, 0, 0, 0);
                }
                #pragma unroll
                for (int r = 0; r < 4; ++r){
                    int tok = m0 + quad*4 + r;         // always <49
                    float v = acc[r] + bias;
                    if (m == 0)      qh[tok*QK_ST + dl] = tob(v * SCALEQ);
                    else if (m == 1) kh[tok*QK_ST + dl] = tob(v);
                    else             vT[dl*VT_ST + tok] = tob(v);
                }
            }
        }
        __syncthreads();
        // ---- phase 2a: scores S = q k^T + bias (+mask).  16 tiles ----
        #pragma unroll
        for (int i = 0; i < 2; ++i){
            int tau = wv + 8*i;              // 0..15
            int mt = tau & 3, nt = tau >> 2;
            int m0 = mt0(mt), n0 = mt0(nt);
            bf16x8v afr = ldfrag(qh + (m0 + li16)*QK_ST + quad*8);
            bf16x8v bfr = ldfrag(kh + (n0 + li16)*QK_ST + quad*8);
            f32x4 acc = {0.f,0.f,0.f,0.f};
            acc = __builtin_amdgcn_mfma_f32_16x16x32_bf16(afr, bfr, acc, 0, 0, 0);
            int col = n0 + li16;
            int yj = col / WSS, xj = col % WSS;
            #pragma unroll
            for (int r = 0; r < 4; ++r){
                int row = m0 + quad*4 + r;
                int yi = row / WSS, xi = row % WSS;
                int ridx = (yi - yj + WSS-1)*(2*WSS-1) + (xi - xj + WSS-1);
                float v = acc[r] + tof(rpb[ridx*NHH + h]);
                if (masked){
                    int ayi = wh*WSS + yi, axi = ww*WSS + xi;
                    int ayj = wh*WSS + yj, axj = ww*WSS + xj;
                    int li = ((ayi<49)?0:(ayi<53)?1:2)*3 + ((axi<49)?0:(axi<53)?1:2);
                    int lj = ((ayj<49)?0:(ayj<53)?1:2)*3 + ((axj<49)?0:(axj<53)?1:2);
                    if (li != lj) v -= 100.f;
                }
                sc[row*SC_ST + col] = v;
            }
        }
        __syncthreads();
        // ---- softmax rows, one thread per row; write P (bf16, pad cols 0) ----
        if (t < NN){
            float* r = sc + t*SC_ST;
            float mx = -1e30f;
            for (int j = 0; j < NN; ++j) mx = fmaxf(mx, r[j]);
            float s = 0.f;
            for (int j = 0; j < NN; ++j){ float e = __expf(r[j]-mx); r[j] = e; s += e; }
            float inv = 1.f/s;
            bf16* pr = P + t*P_ST;
            for (int j = 0; j < NN; ++j) pr[j] = tob(r[j]*inv);
            for (int j = NN; j < 64; ++j) pr[j] = tob(0.f);
        }
        __syncthreads();
        // ---- phase 2c: O = P V.  8 tiles = 4 mt x 2 nt, K=64 ----
        {
            int mt = wv & 3, nt = wv >> 2;
            int m0 = mt0(mt), n0 = nt*16;
            f32x4 acc = {0.f,0.f,0.f,0.f};
            #pragma unroll
            for (int kc = 0; kc < 2; ++kc){
                bf16x8v afr = ldfrag(P  + (m0 + li16)*P_ST  + kc*32 + quad*8);
                bf16x8v bfr = ldfrag(vT + (n0 + li16)*VT_ST + kc*32 + quad*8);
                acc = __builtin_amdgcn_mfma_f32_16x16x32_bf16(afr, bfr, acc, 0, 0, 0);
            }
            #pragma unroll
            for (int r = 0; r < 4; ++r){
                int tok = m0 + quad*4 + r;   // <49
                AOut[(size_t)win*NN*CC + tok*CC + h*HDD + n0 + li16] = tob(acc[r]);
            }
        }
        __syncthreads();
    }
}

// ---------- proj (MFMA) + window reverse + roll-by-WS bug + residual ----------
#define AS_STRIDE 200
template<typename XT>
__global__ __launch_bounds__(256) void k_proj_res(const bf16* __restrict__ AOut,
        const bf16* __restrict__ pw, const bf16* __restrict__ pb,
        XT* __restrict__ X, int shift){
    __shared__ bf16 as[32*AS_STRIDE];
    int t = threadIdx.x;
    int row0 = blockIdx.x * 32;
    for (int idx = t; idx < 32*CC; idx += 256){
        int r = idx / CC, c = idx % CC;
        as[r*AS_STRIDE + c] = AOut[(size_t)(row0 + r)*CC + c];
    }
    __syncthreads();
    int wv = t >> 6, lane = t & 63;
    int li16 = lane & 15, quad = lane >> 4;
    int roll = (shift > 0) ? WSS : 0;
    for (int nt = 0; nt < 3; ++nt){
        int n0 = wv*48 + nt*16;
        int col = n0 + li16;
        bf16x8v bfr[6];
        #pragma unroll
        for (int kc = 0; kc < 6; ++kc)
            bfr[kc] = ldfrag(pw + (size_t)col*CC + kc*32 + quad*8);
        float bias = tof(pb[col]);
        for (int mt = 0; mt < 2; ++mt){
            int m0 = mt*16;
            f32x4 acc = {0.f,0.f,0.f,0.f};
            #pragma unroll
            for (int kc = 0; kc < 6; ++kc){
                bf16x8v afr = ldfrag(as + (m0 + li16)*AS_STRIDE + kc*32 + quad*8);
                acc = __builtin_amdgcn_mfma_f32_16x16x32_bf16(afr, bfr[kc], acc, 0, 0, 0);
            }
            #pragma unroll
            for (int r = 0; r < 4; ++r){
                int grow = row0 + m0 + quad*4 + r;
                int b   = grow / (NWIN*NN);
                int rem = grow % (NWIN*NN);
                int win = rem / NN;
                int n   = rem % NN;
                int wh = win >> 3, ww = win & 7;
                int iy = n / WSS, ix = n % WSS;
                int y = (wh*WSS + iy + roll) % HH;
                int x = (ww*WSS + ix + roll) % WWI;
                size_t idx = ((size_t)(b*LL + y*WWI + x))*CC + col;
                xstore(&X[idx], xload(&X[idx]) + acc[r] + bias);
            }
        }
    }
}

// ---------- LN2 + FC1(MFMA) + GELU + FC2(MFMA) + residual ----------
#define H1_STRIDE 776
template<typename XT>
__global__ __launch_bounds__(256) void k_mlp(XT* __restrict__ X,
        const bf16* __restrict__ n2w, const bf16* __restrict__ n2b,
        const bf16* __restrict__ w1, const bf16* __restrict__ b1,
        const bf16* __restrict__ w2, const bf16* __restrict__ b2){
    __shared__ bf16  xin[32*AS_STRIDE];
    __shared__ bf16  h1[32*H1_STRIDE];
    __shared__ float part[256], part2[256];
    __shared__ float stats[64];
    int t = threadIdx.x;
    size_t row0 = (size_t)blockIdx.x * 32;
    {
        int r = t >> 3, s = t & 7;
        const XT* xr = X + (row0 + r)*CC + s*24;
        float sm = 0.f, sm2 = 0.f;
        #pragma unroll
        for (int c = 0; c < 24; ++c){ float v = xload(&xr[c]); sm += v; sm2 += v*v; }
        part[t] = sm; part2[t] = sm2;
    }
    __syncthreads();
    if (t < 32){
        float s = 0.f, s2 = 0.f;
        #pragma unroll
        for (int k = 0; k < 8; ++k){ s += part[t*8+k]; s2 += part2[t*8+k]; }
        float mu  = s * (1.f/CC);
        float var = s2 * (1.f/CC) - mu*mu;
        stats[t]      = mu;
        stats[32 + t] = rsqrtf(var + 1e-5f);
    }
    __syncthreads();
    for (int idx = t; idx < 32*CC; idx += 256){
        int r = idx / CC, c = idx % CC;
        float v = xload(&X[(row0 + r)*CC + c]);
        xin[r*AS_STRIDE + c] = tob((v - stats[r]) * stats[32+r] * tof(n2w[c]) + tof(n2b[c]));
    }
    __syncthreads();
    int wv = t >> 6, lane = t & 63;
    int li16 = lane & 15, quad = lane >> 4;
    for (int nt = 0; nt < 12; ++nt){
        int n0 = wv*192 + nt*16;
        int col = n0 + li16;
        bf16x8v bfr[6];
        #pragma unroll
        for (int kc = 0; kc < 6; ++kc)
            bfr[kc] = ldfrag(w1 + (size_t)col*CC + kc*32 + quad*8);
        float bb = tof(b1[col]);
        for (int mt = 0; mt < 2; ++mt){
            int m0 = mt*16;
            f32x4 acc = {0.f,0.f,0.f,0.f};
            #pragma unroll
            for (int kc = 0; kc < 6; ++kc){
                bf16x8v afr = ldfrag(xin + (m0 + li16)*AS_STRIDE + kc*32 + quad*8);
                acc = __builtin_amdgcn_mfma_f32_16x16x32_bf16(afr, bfr[kc], acc, 0, 0, 0);
            }
            #pragma unroll
            for (int r = 0; r < 4; ++r){
                int mrow = m0 + quad*4 + r;
                float xv = acc[r] + bb;
                float g  = 0.5f*xv*(1.f + erff(xv*0.70710678118f));
                h1[mrow*H1_STRIDE + col] = tob(g);
            }
        }
    }
    __syncthreads();
    for (int nt = 0; nt < 3; ++nt){
        int n0 = wv*48 + nt*16;
        int col = n0 + li16;
        f32x4 acc0 = {0.f,0.f,0.f,0.f};
        f32x4 acc1 = {0.f,0.f,0.f,0.f};
        for (int kc = 0; kc < 24; ++kc){
            bf16x8v bfr = ldfrag(w2 + (size_t)col*768 + kc*32 + quad*8);
            bf16x8v a0  = ldfrag(h1 + (0  + li16)*H1_STRIDE + kc*32 + quad*8);
            bf16x8v a1  = ldfrag(h1 + (16 + li16)*H1_STRIDE + kc*32 + quad*8);
            acc0 = __builtin_amdgcn_mfma_f32_16x16x32_bf16(a0, bfr, acc0, 0, 0, 0);
            acc1 = __builtin_amdgcn_mfma_f32_16x16x32_bf16(a1, bfr, acc1, 0, 0, 0);
        }
        float bias = tof(b2[col]);
        #pragma unroll
        for (int r = 0; r < 4; ++r){
            size_t i0 = (row0 + 0  + quad*4 + r)*CC + col;
            size_t i1 = (row0 + 16 + quad*4 + r)*CC + col;
            xstore(&X[i0], xload(&X[i0]) + acc0[r] + bias);
            xstore(&X[i1], xload(&X[i1]) + acc1[r] + bias);
        }
    }
}

// ---------- driver ----------
template<typename XT>
static void run_pipeline(const bf16* wb, const void* xin, int* flag,
                         XT* X, bf16* Hwin, bf16* AOut, void* out,
                         hipStream_t stream){
    k_convert_in<XT><<<(int)(TOT/256), 256, 0, stream>>>(xin, X, flag);
    for (int i = 0; i < 2; ++i){
        int shift = i ? (WSS/2) : 0;
        k_ln_part<XT><<<ROWS, CC, 0, stream>>>(X, wb+OFF_N1W + i*CC,
                wb+OFF_N1B + i*CC, Hwin, shift);
        k_attn<<<BB*NWIN, 512, 0, stream>>>(Hwin,
                wb+OFF_QKVW + (size_t)i*3*CC*CC, wb+OFF_QKVB + (size_t)i*3*CC,
                wb+OFF_RPB + (size_t)i*169*NHH, AOut, i);
        k_proj_res<XT><<<ROWS/32, 256, 0, stream>>>(AOut,
                wb+OFF_PROJW + (size_t)i*CC*CC, wb+OFF_PROJB + i*CC, X, shift);
        k_mlp<XT><<<ROWS/32, 256, 0, stream>>>(X,
                wb+OFF_N2W + i*CC, wb+OFF_N2B + i*CC,
                wb+OFF_F1W + (size_t)i*4*CC*CC, wb+OFF_F1B + (size_t)i*4*CC,
                wb+OFF_F2W + (size_t)i*CC*4*CC, wb+OFF_F2B + i*CC);
    }
    k_out<XT><<<(int)(TOT/256), 256, 0, stream>>>(X, out, flag);
}

extern "C" void kernel_launch(void* const* d_in, const int* in_sizes, int n_in,
                              void* d_out, int out_size, void* d_ws, size_t ws_size,
                              hipStream_t stream){
    char* p = (char*)d_ws;
    int*  flag = (int*)p;
    bf16* wb   = (bf16*)(p + 16);
    char* q    = p + 16 + (2u<<20);

    k_detect<<<1, 64, 0, stream>>>((const unsigned short*)d_in[1], flag);

    static const int widx[13] = {1,2,3,4,5,6,7,8,9,10,11,12,13};
    static const int woff[13] = {OFF_N1W,OFF_N1B,OFF_QKVW,OFF_QKVB,OFF_RPB,
                                 OFF_PROJW,OFF_PROJB,OFF_N2W,OFF_N2B,
                                 OFF_F1W,OFF_F1B,OFF_F2W,OFF_F2B};
    static const int wsz[13]  = {384,384,221184,1152,2028,73728,384,384,384,
                                 294912,1536,294912,384};
    for (int k = 0; k < 13; ++k)
        k_canon<<<(wsz[k]+255)/256, 256, 0, stream>>>(d_in[widx[k]], wb+woff[k],
                                                      wsz[k], flag);

    size_t needF32 = 16 + (2u<<20) + TOT*4 + TOT*2 + TOT*2;
    if (ws_size >= needF32){
        float* X   = (float*)q;       q += TOT*4;
        bf16* Hwin = (bf16*)q;        q += TOT*2;
        bf16* AOut = (bf16*)q;
        run_pipeline<float>(wb, d_in[0], flag, X, Hwin, AOut, d_out, stream);
    } else {
        bf16* X    = (bf16*)q;        q += TOT*2;
        bf16* Hwin = (bf16*)q;        q += TOT*2;
        bf16* AOut = (bf16*)q;
        run_pipeline<bf16>(wb, d_in[0], flag, X, Hwin, AOut, d_out, stream);
    }
}